// Round 1
// baseline (177.598 us; speedup 1.0000x reference)
//
#include <hip/hip_runtime.h>

#define NFEAS 4096
#define HID   128
#define BATCH 128
#define NC    32          // number of chunks
#define K     (NFEAS/NC)  // 128 features per chunk

// ---------------------------------------------------------------------------
// Phase A: per-(sample, chunk) partial sums of x_f * W[f,:]  ->  T[b,c,h]
// 64 threads/block; thread t owns hidden units t and t+64.
// ---------------------------------------------------------------------------
__global__ __launch_bounds__(64) void chunk_sums_kernel(
    const float* __restrict__ x, const float* __restrict__ W,
    float* __restrict__ T)
{
    const int b = blockIdx.x, c = blockIdx.y, t = threadIdx.x;
    const int base = c * K;

    // pre-ballot the x>0 bits for this chunk: bit i of mlo = (x[b,base+i] > 0)
    const unsigned long long mlo = __ballot(x[(size_t)b * NFEAS + base + t]      > 0.f);
    const unsigned long long mhi = __ballot(x[(size_t)b * NFEAS + base + 64 + t] > 0.f);

    float s0 = 0.f, s1 = 0.f;
    for (int i = 0; i < K; ++i) {
        const int f = base + i;
        const bool xf = (i < 64) ? ((mlo >> (unsigned)i) & 1ull)
                                 : ((mhi >> (unsigned)(i - 64)) & 1ull);
        if (xf) {  // wave-uniform branch
            s0 += W[(size_t)f * HID + t];
            s1 += W[(size_t)f * HID + 64 + t];
        }
    }
    float* Trow = T + ((size_t)b * NC + c) * HID;
    Trow[t]      = s0;
    Trow[64 + t] = s1;
}

// ---------------------------------------------------------------------------
// Phase C: per-(sample, chunk) sequential scan of K features.
// Start state = sum of all previous chunks' totals (exclusive prefix).
// 64 threads/block (1 wave): dot-reduce via shfl_xor butterfly, no barriers.
// ---------------------------------------------------------------------------
__global__ __launch_bounds__(64) void chunk_loss_kernel(
    const float* __restrict__ x,  const float* __restrict__ Cv,
    const float* __restrict__ W,  const float* __restrict__ Bv,
    const float* __restrict__ T,  float* __restrict__ losses)
{
    const int b = blockIdx.x, c = blockIdx.y, t = threadIdx.x;
    const int base = c * K;

    // exclusive prefix over chunk totals
    float s0 = 0.f, s1 = 0.f;
    for (int cp = 0; cp < c; ++cp) {
        const float* Trow = T + ((size_t)b * NC + cp) * HID;
        s0 += Trow[t];
        s1 += Trow[64 + t];
    }

    const float c0 = Cv[t], c1 = Cv[64 + t];

    const unsigned long long mlo = __ballot(x[(size_t)b * NFEAS + base + t]      > 0.f);
    const unsigned long long mhi = __ballot(x[(size_t)b * NFEAS + base + 64 + t] > 0.f);

    float loss = 0.f;
    for (int i = 0; i < K; ++i) {
        const int f = base + i;
        const float w0 = W[(size_t)f * HID + t];
        const float w1 = W[(size_t)f * HID + 64 + t];

        float h0, h1;
        if (f == 0) {          // faithful quirk: raw C, no sigmoid, at feature 0
            h0 = c0; h1 = c1;
        } else {
            h0 = 1.f / (1.f + __expf(-(s0 + c0)));
            h1 = 1.f / (1.f + __expf(-(s1 + c1)));
        }

        float p = h0 * w0 + h1 * w1;
        #pragma unroll
        for (int off = 32; off >= 1; off >>= 1)
            p += __shfl_xor(p, off, 64);     // all lanes end with full dot

        const float z = p + Bv[f];
        const bool xf = (i < 64) ? ((mlo >> (unsigned)i) & 1ull)
                                 : ((mhi >> (unsigned)(i - 64)) & 1ull);

        // stable BCE: max(z,0) - z*x + log1p(exp(-|z|))
        loss += fmaxf(z, 0.f) - (xf ? z : 0.f) + log1pf(__expf(-fabsf(z)));

        if (xf) {  // wave-uniform
            s0 += w0;
            s1 += w1;
        }
    }

    if (t == 0) losses[(size_t)b * NC + c] = loss;
}

// ---------------------------------------------------------------------------
// Finalize: deterministic reduction of the BATCH*NC per-chunk losses -> mean.
// ---------------------------------------------------------------------------
__global__ __launch_bounds__(256) void finalize_kernel(
    const float* __restrict__ losses, float* __restrict__ out)
{
    __shared__ float sm[256];
    const int t = threadIdx.x;
    float s = 0.f;
    for (int i = t; i < BATCH * NC; i += 256) s += losses[i];
    sm[t] = s;
    __syncthreads();
    for (int w = 128; w > 0; w >>= 1) {
        if (t < w) sm[t] += sm[t + w];
        __syncthreads();
    }
    if (t == 0) out[0] = sm[0] * (1.f / BATCH);
}

// ---------------------------------------------------------------------------
extern "C" void kernel_launch(void* const* d_in, const int* in_sizes, int n_in,
                              void* d_out, int out_size, void* d_ws, size_t ws_size,
                              hipStream_t stream)
{
    const float* x  = (const float*)d_in[0];  // [BATCH, NFEAS]
    const float* Cv = (const float*)d_in[1];  // [1, HID]
    const float* W  = (const float*)d_in[2];  // [NFEAS, HID]
    const float* Bv = (const float*)d_in[3];  // [NFEAS]
    float* out = (float*)d_out;

    float* T      = (float*)d_ws;                       // [BATCH, NC, HID]
    float* losses = T + (size_t)BATCH * NC * HID;       // [BATCH * NC]

    dim3 grid(BATCH, NC);
    chunk_sums_kernel<<<grid, 64, 0, stream>>>(x, W, T);
    chunk_loss_kernel<<<grid, 64, 0, stream>>>(x, Cv, W, Bv, T, losses);
    finalize_kernel<<<1, 256, 0, stream>>>(losses, out);
}

// Round 3
// 78.651 us; speedup vs baseline: 2.2580x; 2.2580x over previous
//
#include <hip/hip_runtime.h>

#define NFEAS 4096
#define HID   128
#define BATCH 128
#define NC    64          // chunks
#define K     64          // features per chunk (= wave width)
#define L2E   1.4426950408889634f
#define LN2   0.6931471805599453f

// 64-lane inclusive prefix sum, pure DPP (canonical GCN sequence):
// row_shr 1,2,4,8 (full masks) then row_bcast15 (row_mask 0xA: rows 1,3)
// and row_bcast31 (row_mask 0xC: rows 2,3). bound_ctrl=1 -> invalid lanes
// read 0; row-masked lanes receive old (=0) -> add is a no-op there.
__device__ __forceinline__ float scan64(float v) {
  float r = v; int y;
  y = __builtin_amdgcn_update_dpp(0, __float_as_int(r), 0x111, 0xF, 0xF, true); r += __int_as_float(y);
  y = __builtin_amdgcn_update_dpp(0, __float_as_int(r), 0x112, 0xF, 0xF, true); r += __int_as_float(y);
  y = __builtin_amdgcn_update_dpp(0, __float_as_int(r), 0x114, 0xF, 0xF, true); r += __int_as_float(y);
  y = __builtin_amdgcn_update_dpp(0, __float_as_int(r), 0x118, 0xF, 0xF, true); r += __int_as_float(y);
  y = __builtin_amdgcn_update_dpp(0, __float_as_int(r), 0x142, 0xA, 0xF, true); r += __int_as_float(y);
  y = __builtin_amdgcn_update_dpp(0, __float_as_int(r), 0x143, 0xC, 0xF, true); r += __int_as_float(y);
  return r;
}

// ---------------------------------------------------------------------------
// Phase A: T[b,c,h] = sum_{f in chunk c} (x[b,f]>0) * W[f,h]
// ---------------------------------------------------------------------------
__global__ __launch_bounds__(64) void chunk_sums_kernel(
    const float* __restrict__ x, const float* __restrict__ W,
    float* __restrict__ T)
{
  const int b = blockIdx.x, c = blockIdx.y, t = threadIdx.x;
  const int base = c * K;
  const unsigned long long m = __ballot(x[(size_t)b * NFEAS + base + t] > 0.f);
  float s0 = 0.f, s1 = 0.f;
  for (int i = 0; i < K; ++i) {
    if ((m >> (unsigned)i) & 1ull) {   // wave-uniform branch
      const float* wr = W + (size_t)(base + i) * HID;
      s0 += wr[t];
      s1 += wr[64 + t];
    }
  }
  float* Tr = T + ((size_t)b * NC + c) * HID;
  Tr[t] = s0; Tr[64 + t] = s1;
}

// ---------------------------------------------------------------------------
// Phase B: in-place exclusive prefix over c of T[b,:,h]. One thread per (b,h).
// ---------------------------------------------------------------------------
__global__ __launch_bounds__(256) void prefix_kernel(float* __restrict__ T)
{
  const int idx = blockIdx.x * 256 + threadIdx.x;   // BATCH*HID = 16384
  const int b = idx >> 7, h = idx & 127;
  float* p = T + (size_t)b * NC * HID + h;
  float run = 0.f;
  #pragma unroll 8
  for (int c = 0; c < NC; ++c) {
    const float v = p[(size_t)c * HID];
    p[(size_t)c * HID] = run;
    run += v;
  }
}

// ---------------------------------------------------------------------------
// Phase C: per (b, chunk): lane = feature, loop over h.
//   S_excl[f,h] = start[h] + prefix_{j<f}(m_j * W[j,h])  via DPP scan
//   z_f += sigmoid(S_excl + C) * W[f,h]; BCE lane-parallel in epilogue.
// 4 waves split the 128 h's; W^T staged in LDS with q-XOR swizzle.
// ---------------------------------------------------------------------------
template<bool C0>
__global__ __launch_bounds__(256) void scan_loss_kernel(
    const float* __restrict__ x,  const float* __restrict__ Cv,
    const float* __restrict__ W,  const float* __restrict__ Bv,
    const float* __restrict__ T,  float* __restrict__ losses, int cOff)
{
  __shared__ float wt[128 * 64];   // wt[h][f ^ ((h>>5)<<4)] = W[base+f][h]
  __shared__ float s2m[128];       // -(start+C)*log2e
  __shared__ float s2r[128];       // start+C (for the f==0 raw-C quirk)
  __shared__ float zbuf[4 * 64];

  const int tid = threadIdx.x;
  const int b = blockIdx.x, c = blockIdx.y + cOff;
  const int base = c * K;

  { // stage W^T: thread = (row f = tid>>2, quarter q = tid&3), float4 loads
    const int f = tid >> 2, q = tid & 3;
    const int col = f ^ (q << 4);
    const float* wrow = W + (size_t)(base + f) * HID + q * 32;
    #pragma unroll
    for (int kk = 0; kk < 8; ++kk) {
      const float4 v = reinterpret_cast<const float4*>(wrow)[kk];
      const int h = q * 32 + kk * 4;
      wt[(h + 0) * 64 + col] = v.x;
      wt[(h + 1) * 64 + col] = v.y;
      wt[(h + 2) * 64 + col] = v.z;
      wt[(h + 3) * 64 + col] = v.w;
    }
  }
  if (tid < 128) {
    const float s2 = T[((size_t)b * NC + c) * HID + tid] + Cv[tid];
    s2r[tid] = s2;
    s2m[tid] = -L2E * s2;
  }

  const int lane = tid & 63, wid = tid >> 6;
  const float xv = x[(size_t)b * NFEAS + base + lane];
  const float xm = xv > 0.f ? 1.f : 0.f;

  __syncthreads();

  float z = 0.f;
  const int rbase = (wid * 32) * 64 + (lane ^ (wid << 4));
  #pragma unroll
  for (int hh = 0; hh < 32; ++hh) {
    const int h = wid * 32 + hh;
    const float w  = wt[rbase + hh * 64];
    const float mw = w * xm;
    const float r  = scan64(mw);
    const float ex = r - mw;                     // exclusive prefix
    float sig = __builtin_amdgcn_rcpf(
        1.0f + __builtin_amdgcn_exp2f(__builtin_fmaf(ex, -L2E, s2m[h])));
    if (C0) {
      if (lane == 0) sig = ex + s2r[h];          // raw C at global feature 0
    }
    z = __builtin_fmaf(sig, w, z);
  }
  zbuf[wid * 64 + lane] = z;
  __syncthreads();

  if (wid == 0) {
    const float zt = zbuf[lane] + zbuf[64 + lane] + zbuf[128 + lane] +
                     zbuf[192 + lane] + Bv[base + lane];
    const float az = __builtin_fabsf(zt);
    const float ee = __builtin_amdgcn_exp2f(-L2E * az);
    const float li = fmaxf(zt, 0.f) - xm * zt +
                     LN2 * __builtin_amdgcn_logf(1.0f + ee);
    const float tot = scan64(li);                // lane 63 holds the chunk sum
    if (lane == 63) losses[b * NC + c] = tot;
  }
}

// ---------------------------------------------------------------------------
// Finalize: deterministic reduction of BATCH*NC chunk losses -> mean.
// ---------------------------------------------------------------------------
__global__ __launch_bounds__(256) void finalize_kernel(
    const float* __restrict__ losses, float* __restrict__ out)
{
  __shared__ float sm[256];
  const int t = threadIdx.x;
  float s = 0.f;
  for (int i = t; i < BATCH * NC; i += 256) s += losses[i];
  sm[t] = s;
  __syncthreads();
  for (int w = 128; w > 0; w >>= 1) {
    if (t < w) sm[t] += sm[t + w];
    __syncthreads();
  }
  if (t == 0) out[0] = sm[0] * (1.f / BATCH);
}

// ---------------------------------------------------------------------------
extern "C" void kernel_launch(void* const* d_in, const int* in_sizes, int n_in,
                              void* d_out, int out_size, void* d_ws, size_t ws_size,
                              hipStream_t stream)
{
  const float* x  = (const float*)d_in[0];  // [BATCH, NFEAS]
  const float* Cv = (const float*)d_in[1];  // [1, HID]
  const float* W  = (const float*)d_in[2];  // [NFEAS, HID]
  const float* Bv = (const float*)d_in[3];  // [NFEAS]
  float* out = (float*)d_out;

  float* T      = (float*)d_ws;                      // [BATCH, NC, HID] 4 MB
  float* losses = T + (size_t)BATCH * NC * HID;      // [BATCH * NC]

  chunk_sums_kernel<<<dim3(BATCH, NC), 64, 0, stream>>>(x, W, T);
  prefix_kernel<<<dim3(BATCH * HID / 256), 256, 0, stream>>>(T);
  scan_loss_kernel<true ><<<dim3(BATCH, 1),      256, 0, stream>>>(x, Cv, W, Bv, T, losses, 0);
  scan_loss_kernel<false><<<dim3(BATCH, NC - 1), 256, 0, stream>>>(x, Cv, W, Bv, T, losses, 1);
  finalize_kernel<<<1, 256, 0, stream>>>(losses, out);
}

// Round 4
// 64.956 us; speedup vs baseline: 2.7342x; 1.2109x over previous
//
#include <hip/hip_runtime.h>

#define NFEAS 4096
#define HID   128
#define BATCH 128
#define NSUB  64          // T granularity: 64 sub-chunks of 64 features
#define NC    16          // scan chunks of KF features
#define KF    256
#define L2E   1.4426950408889634f
#define LN2   0.6931471805599453f

// 64-lane inclusive prefix sum, fused DPP adds (canonical GCN sequence).
__device__ __forceinline__ float scan64(float v) {
  float r = v; int y;
  y = __builtin_amdgcn_update_dpp(0, __float_as_int(r), 0x111, 0xF, 0xF, true); r += __int_as_float(y);
  y = __builtin_amdgcn_update_dpp(0, __float_as_int(r), 0x112, 0xF, 0xF, true); r += __int_as_float(y);
  y = __builtin_amdgcn_update_dpp(0, __float_as_int(r), 0x114, 0xF, 0xF, true); r += __int_as_float(y);
  y = __builtin_amdgcn_update_dpp(0, __float_as_int(r), 0x118, 0xF, 0xF, true); r += __int_as_float(y);
  y = __builtin_amdgcn_update_dpp(0, __float_as_int(r), 0x142, 0xA, 0xF, true); r += __int_as_float(y);
  y = __builtin_amdgcn_update_dpp(0, __float_as_int(r), 0x143, 0xC, 0xF, true); r += __int_as_float(y);
  return r;
}

// ---------------------------------------------------------------------------
// Phase A: T[b][h][c] = sum_{f in 64-subchunk c} (x[b,f]>0) * W[f,h]
// (scattered 4B stores; L2-resident, prefix pass then reads coalesced)
// ---------------------------------------------------------------------------
__global__ __launch_bounds__(64) void chunk_sums_kernel(
    const float* __restrict__ x, const float* __restrict__ W,
    float* __restrict__ T)
{
  const int b = blockIdx.x, c = blockIdx.y, t = threadIdx.x;
  const int base = c * 64;
  const unsigned long long m = __ballot(x[(size_t)b * NFEAS + base + t] > 0.f);
  float s0 = 0.f, s1 = 0.f;
  for (int i = 0; i < 64; ++i) {
    if ((m >> (unsigned)i) & 1ull) {   // wave-uniform branch
      const float* wr = W + (size_t)(base + i) * HID;
      s0 += wr[t];
      s1 += wr[64 + t];
    }
  }
  T[((size_t)b * HID + t) * NSUB + c]      = s0;
  T[((size_t)b * HID + t + 64) * NSUB + c] = s1;
}

// ---------------------------------------------------------------------------
// Phase B: in-place exclusive scan of T[b][h][0..63] — one wave per (b,h).
// ---------------------------------------------------------------------------
__global__ __launch_bounds__(256) void prefix_kernel(float* __restrict__ T)
{
  const int gw = blockIdx.x * 4 + (threadIdx.x >> 6);  // (b,h) id, 16384 total
  const int lane = threadIdx.x & 63;
  float* p = T + (size_t)gw * NSUB;
  const float v = p[lane];
  const float r = scan64(v);
  p[lane] = r - v;                                     // exclusive
}

// ---------------------------------------------------------------------------
// Phase C: block = (b, chunk of 256 f). 512 threads / 8 waves.
// Lane owns 4 consecutive features; one DPP scan per 4 features.
// W^T tile processed as 4 slices of [32 h][256 f] (32 KB LDS, restaged).
// ---------------------------------------------------------------------------
__global__ __launch_bounds__(512, 6) void scan_loss_kernel(
    const float* __restrict__ x,  const float* __restrict__ Cv,
    const float* __restrict__ W,  const float* __restrict__ Bv,
    const float* __restrict__ T,  float* __restrict__ losses)
{
  __shared__ float wt[32 * 256];   // slice tile; reused as zbuf in epilogue
  __shared__ float s2m[HID];       // -(start+C)*log2e
  __shared__ float s2r[HID];       // start+C (raw-C quirk)
  __shared__ float lred[8];

  const int tid = threadIdx.x;
  const int b = blockIdx.x, c = blockIdx.y;
  const int base = c * KF;
  const int lane = tid & 63, w = tid >> 6;

  if (tid < HID) {
    const float s2 = T[((size_t)b * HID + tid) * NSUB + c * 4] + Cv[tid];
    s2r[tid] = s2;
    s2m[tid] = -L2E * s2;
  }

  const float4 xv = *reinterpret_cast<const float4*>(
      x + (size_t)b * NFEAS + base + 4 * lane);
  const float xm0 = xv.x > 0.f ? 1.f : 0.f;
  const float xm1 = xv.y > 0.f ? 1.f : 0.f;
  const float xm2 = xv.z > 0.f ? 1.f : 0.f;
  const float xm3 = xv.w > 0.f ? 1.f : 0.f;

  float z0 = 0.f, z1 = 0.f, z2 = 0.f, z3 = 0.f;

  const int fst = tid & 255;          // staging feature
  const int hh2 = tid >> 8;           // staging h-half (0/1)
  const float* wrow = W + (size_t)(base + fst) * HID;
  const bool quirk = (c == 0);

  for (int hq = 0; hq < 4; ++hq) {
    if (hq) __syncthreads();          // WAR: previous slice consumed
    #pragma unroll
    for (int k = 0; k < 4; ++k) {
      const float4 v = *reinterpret_cast<const float4*>(
          wrow + hq * 32 + hh2 * 16 + k * 4);
      const int h = hh2 * 16 + k * 4;
      wt[(h + 0) * 256 + fst] = v.x;
      wt[(h + 1) * 256 + fst] = v.y;
      wt[(h + 2) * 256 + fst] = v.z;
      wt[(h + 3) * 256 + fst] = v.w;
    }
    __syncthreads();
    #pragma unroll
    for (int j = 0; j < 4; ++j) {
      const int hl = w * 4 + j;                 // slice-local h
      const int h  = hq * 32 + hl;              // global h
      const float4 wv = *reinterpret_cast<const float4*>(&wt[hl * 256 + 4 * lane]);
      const float mw0 = wv.x * xm0, mw1 = wv.y * xm1;
      const float mw2 = wv.z * xm2, mw3 = wv.w * xm3;
      const float ps = (mw0 + mw1) + (mw2 + mw3);
      const float r  = scan64(ps);
      const float e0 = r - ps;
      const float e1 = e0 + mw0;
      const float e2 = e1 + mw1;
      const float e3 = e2 + mw2;
      const float sm = s2m[h];
      float g0 = __builtin_amdgcn_rcpf(1.f + __builtin_amdgcn_exp2f(__builtin_fmaf(e0, -L2E, sm)));
      float g1 = __builtin_amdgcn_rcpf(1.f + __builtin_amdgcn_exp2f(__builtin_fmaf(e1, -L2E, sm)));
      float g2 = __builtin_amdgcn_rcpf(1.f + __builtin_amdgcn_exp2f(__builtin_fmaf(e2, -L2E, sm)));
      float g3 = __builtin_amdgcn_rcpf(1.f + __builtin_amdgcn_exp2f(__builtin_fmaf(e3, -L2E, sm)));
      if (quirk && lane == 0) g0 = s2r[h];      // raw C at global feature 0
      z0 = __builtin_fmaf(g0, wv.x, z0);
      z1 = __builtin_fmaf(g1, wv.y, z1);
      z2 = __builtin_fmaf(g2, wv.z, z2);
      z3 = __builtin_fmaf(g3, wv.w, z3);
    }
  }

  // cross-wave z reduction (reuse wt as zbuf[8][256])
  __syncthreads();
  {
    float4 zv; zv.x = z0; zv.y = z1; zv.z = z2; zv.w = z3;
    *reinterpret_cast<float4*>(&wt[w * 256 + 4 * lane]) = zv;
  }
  __syncthreads();

  if (tid < 256) {
    float zt = 0.f;
    #pragma unroll
    for (int ww = 0; ww < 8; ++ww) zt += wt[ww * 256 + tid];
    zt += Bv[base + tid];
    const float xf = x[(size_t)b * NFEAS + base + tid] > 0.f ? 1.f : 0.f;
    const float az = __builtin_fabsf(zt);
    const float ee = __builtin_amdgcn_exp2f(-L2E * az);
    const float li = fmaxf(zt, 0.f) - xf * zt +
                     LN2 * __builtin_amdgcn_logf(1.f + ee);
    const float tot = scan64(li);
    if ((tid & 63) == 63) lred[tid >> 6] = tot;
  }
  __syncthreads();
  if (tid == 0)
    losses[b * NC + c] = (lred[0] + lred[1]) + (lred[2] + lred[3]);
}

// ---------------------------------------------------------------------------
// Finalize: deterministic reduction of BATCH*NC chunk losses -> mean.
// ---------------------------------------------------------------------------
__global__ __launch_bounds__(256) void finalize_kernel(
    const float* __restrict__ losses, float* __restrict__ out)
{
  __shared__ float sm[256];
  const int t = threadIdx.x;
  float s = 0.f;
  for (int i = t; i < BATCH * NC; i += 256) s += losses[i];
  sm[t] = s;
  __syncthreads();
  for (int w = 128; w > 0; w >>= 1) {
    if (t < w) sm[t] += sm[t + w];
    __syncthreads();
  }
  if (t == 0) out[0] = sm[0] * (1.f / BATCH);
}

// ---------------------------------------------------------------------------
extern "C" void kernel_launch(void* const* d_in, const int* in_sizes, int n_in,
                              void* d_out, int out_size, void* d_ws, size_t ws_size,
                              hipStream_t stream)
{
  const float* x  = (const float*)d_in[0];  // [BATCH, NFEAS]
  const float* Cv = (const float*)d_in[1];  // [1, HID]
  const float* W  = (const float*)d_in[2];  // [NFEAS, HID]
  const float* Bv = (const float*)d_in[3];  // [NFEAS]
  float* out = (float*)d_out;

  float* T      = (float*)d_ws;                        // [B][HID][NSUB] 4 MB
  float* losses = T + (size_t)BATCH * HID * NSUB;      // [BATCH * NC]

  chunk_sums_kernel<<<dim3(BATCH, NSUB), 64, 0, stream>>>(x, W, T);
  prefix_kernel<<<dim3(BATCH * HID / 4), 256, 0, stream>>>(T);
  scan_loss_kernel<<<dim3(BATCH, NC), 512, 0, stream>>>(x, Cv, W, Bv, T, losses);
  finalize_kernel<<<1, 256, 0, stream>>>(losses, out);
}

// Round 5
// 55.237 us; speedup vs baseline: 3.2152x; 1.1759x over previous
//
#include <hip/hip_runtime.h>

#define NFEAS 4096
#define HID   128
#define BATCH 128
#define NSUB  64          // T granularity: 64 sub-chunks of 64 features
#define NC    16          // scan chunks of KF features
#define KF    256
#define L2E   1.4426950408889634f
#define LN2   0.6931471805599453f

// 64-lane inclusive prefix sum (canonical GCN DPP sequence), single chain.
__device__ __forceinline__ float scan64(float v) {
  float r = v; int y;
  y = __builtin_amdgcn_update_dpp(0, __float_as_int(r), 0x111, 0xF, 0xF, true); r += __int_as_float(y);
  y = __builtin_amdgcn_update_dpp(0, __float_as_int(r), 0x112, 0xF, 0xF, true); r += __int_as_float(y);
  y = __builtin_amdgcn_update_dpp(0, __float_as_int(r), 0x114, 0xF, 0xF, true); r += __int_as_float(y);
  y = __builtin_amdgcn_update_dpp(0, __float_as_int(r), 0x118, 0xF, 0xF, true); r += __int_as_float(y);
  y = __builtin_amdgcn_update_dpp(0, __float_as_int(r), 0x142, 0xA, 0xF, true); r += __int_as_float(y);
  y = __builtin_amdgcn_update_dpp(0, __float_as_int(r), 0x143, 0xC, 0xF, true); r += __int_as_float(y);
  return r;
}

// Four independent 64-lane scans, steps interleaved so the 4 dependency
// chains overlap (hides DPP->VALU latency within one wave).
__device__ __forceinline__ void scan64_x4(float& a, float& b, float& c, float& d) {
  int t0, t1, t2, t3;
#define S4(ctrl, rm)                                                              \
  t0 = __builtin_amdgcn_update_dpp(0, __float_as_int(a), ctrl, rm, 0xF, true);    \
  t1 = __builtin_amdgcn_update_dpp(0, __float_as_int(b), ctrl, rm, 0xF, true);    \
  t2 = __builtin_amdgcn_update_dpp(0, __float_as_int(c), ctrl, rm, 0xF, true);    \
  t3 = __builtin_amdgcn_update_dpp(0, __float_as_int(d), ctrl, rm, 0xF, true);    \
  a += __int_as_float(t0); b += __int_as_float(t1);                               \
  c += __int_as_float(t2); d += __int_as_float(t3);
  S4(0x111, 0xF) S4(0x112, 0xF) S4(0x114, 0xF) S4(0x118, 0xF)
  S4(0x142, 0xA) S4(0x143, 0xC)
#undef S4
}

// ---------------------------------------------------------------------------
// Phase A: T[b][h][c] = sum_{f in 64-subchunk c} (x[b,f]>0) * W[f,h]
// Block = (chunk c, 8-sample group): W row read ONCE per 8 samples (8x less
// L2 traffic), masks broadcast from LDS.
// ---------------------------------------------------------------------------
__global__ __launch_bounds__(128) void chunk_sums_kernel(
    const float* __restrict__ x, const float* __restrict__ W,
    float* __restrict__ T)
{
  __shared__ float xm[64][8];    // xm[f][s]
  const int c = blockIdx.x, g = blockIdx.y, t = threadIdx.x;

  { // stage x>0 masks for 8 samples x 64 features
    const int s = t >> 4, fb = (t & 15) << 2;
    const float4 v = *reinterpret_cast<const float4*>(
        &x[(size_t)(g * 8 + s) * NFEAS + c * 64 + fb]);
    xm[fb + 0][s] = v.x > 0.f ? 1.f : 0.f;
    xm[fb + 1][s] = v.y > 0.f ? 1.f : 0.f;
    xm[fb + 2][s] = v.z > 0.f ? 1.f : 0.f;
    xm[fb + 3][s] = v.w > 0.f ? 1.f : 0.f;
  }
  __syncthreads();

  float acc[8];
  #pragma unroll
  for (int s = 0; s < 8; ++s) acc[s] = 0.f;

  #pragma unroll 4
  for (int f = 0; f < 64; ++f) {
    const float wv = W[(size_t)(c * 64 + f) * HID + t];   // coalesced
    const float4 ma = *reinterpret_cast<const float4*>(&xm[f][0]);  // broadcast
    const float4 mb = *reinterpret_cast<const float4*>(&xm[f][4]);
    acc[0] = __builtin_fmaf(ma.x, wv, acc[0]);
    acc[1] = __builtin_fmaf(ma.y, wv, acc[1]);
    acc[2] = __builtin_fmaf(ma.z, wv, acc[2]);
    acc[3] = __builtin_fmaf(ma.w, wv, acc[3]);
    acc[4] = __builtin_fmaf(mb.x, wv, acc[4]);
    acc[5] = __builtin_fmaf(mb.y, wv, acc[5]);
    acc[6] = __builtin_fmaf(mb.z, wv, acc[6]);
    acc[7] = __builtin_fmaf(mb.w, wv, acc[7]);
  }
  #pragma unroll
  for (int s = 0; s < 8; ++s)
    T[((size_t)(g * 8 + s) * HID + t) * NSUB + c] = acc[s];
}

// ---------------------------------------------------------------------------
// Phase B: in-place exclusive scan of T[b][h][0..63] — one wave per (b,h).
// ---------------------------------------------------------------------------
__global__ __launch_bounds__(256) void prefix_kernel(float* __restrict__ T)
{
  const int gw = blockIdx.x * 4 + (threadIdx.x >> 6);  // (b,h) id, 16384 total
  const int lane = threadIdx.x & 63;
  float* p = T + (size_t)gw * NSUB;
  const float v = p[lane];
  const float r = scan64(v);
  p[lane] = r - v;                                     // exclusive
}

// ---------------------------------------------------------------------------
// Phase C: block = (b, chunk of 256 f). 512 threads / 8 waves.
// Coalesced transposed W staging (XOR-swizzled), 4-way interleaved DPP scans.
// Lane owns features 4*lane..4*lane+3; wave owns 4 h per 32-h slice.
// ---------------------------------------------------------------------------
__global__ __launch_bounds__(512, 4) void scan_loss_kernel(
    const float* __restrict__ x,  const float* __restrict__ Cv,
    const float* __restrict__ W,  const float* __restrict__ Bv,
    const float* __restrict__ T,  float* __restrict__ losses)
{
  __shared__ float wt[32 * 256];   // wt[h][f ^ ((h>>2&3)<<3)]; reused as zbuf
  __shared__ float s2m[HID];       // -(start+C)*log2e
  __shared__ float s2r[HID];       // start+C (raw-C quirk)
  __shared__ float lred[8];

  const int tid = threadIdx.x;
  const int b = blockIdx.x, c = blockIdx.y;
  const int base = c * KF;
  const int lane = tid & 63, w = tid >> 6;

  if (tid < HID) {
    const float s2 = T[((size_t)b * HID + tid) * NSUB + c * 4] + Cv[tid];
    s2r[tid] = s2;
    s2m[tid] = -L2E * s2;
  }

  const float4 xv = *reinterpret_cast<const float4*>(
      x + (size_t)b * NFEAS + base + 4 * lane);
  const float xm0 = xv.x > 0.f ? 1.f : 0.f;
  const float xm1 = xv.y > 0.f ? 1.f : 0.f;
  const float xm2 = xv.z > 0.f ? 1.f : 0.f;
  const float xm3 = xv.w > 0.f ? 1.f : 0.f;

  float z0 = 0.f, z1 = 0.f, z2 = 0.f, z3 = 0.f;

  // staging mapping: thread -> (feature f0, 4h-group hb); reads along h.
  const int hb = tid & 7;
  const int f0 = tid >> 3;                    // 0..63
  const int colw = f0 ^ ((hb & 3) << 3);      // swizzled column (k adds 64k)
  const float* wbase = W + (size_t)base * HID;
  const bool quirk = (c == 0);

  for (int hq = 0; hq < 4; ++hq) {
    if (hq) __syncthreads();          // WAR: previous slice consumed
    #pragma unroll
    for (int k = 0; k < 4; ++k) {
      const int f = f0 + (k << 6);
      const float4 v = *reinterpret_cast<const float4*>(
          wbase + (size_t)f * HID + (hq << 5) + (hb << 2));
      float* wp = &wt[((hb << 2) << 8) + colw + (k << 6)];
      wp[0]   = v.x;
      wp[256] = v.y;
      wp[512] = v.z;
      wp[768] = v.w;
    }
    __syncthreads();

    const int hl0 = w << 2;                       // slice-local h of chain 0
    const int colx = (lane << 2) ^ ((w & 3) << 3);
    const float4 wv0 = *reinterpret_cast<const float4*>(&wt[(hl0 + 0) * 256 + colx]);
    const float4 wv1 = *reinterpret_cast<const float4*>(&wt[(hl0 + 1) * 256 + colx]);
    const float4 wv2 = *reinterpret_cast<const float4*>(&wt[(hl0 + 2) * 256 + colx]);
    const float4 wv3 = *reinterpret_cast<const float4*>(&wt[(hl0 + 3) * 256 + colx]);
    const float4 sm4 = *reinterpret_cast<const float4*>(&s2m[(hq << 5) + hl0]);

    const float m00 = wv0.x * xm0, m01 = wv0.y * xm1, m02 = wv0.z * xm2, m03 = wv0.w * xm3;
    const float m10 = wv1.x * xm0, m11 = wv1.y * xm1, m12 = wv1.z * xm2, m13 = wv1.w * xm3;
    const float m20 = wv2.x * xm0, m21 = wv2.y * xm1, m22 = wv2.z * xm2, m23 = wv2.w * xm3;
    const float m30 = wv3.x * xm0, m31 = wv3.y * xm1, m32 = wv3.z * xm2, m33 = wv3.w * xm3;

    const float ps0 = (m00 + m01) + (m02 + m03);
    const float ps1 = (m10 + m11) + (m12 + m13);
    const float ps2 = (m20 + m21) + (m22 + m23);
    const float ps3 = (m30 + m31) + (m32 + m33);

    float r0 = ps0, r1 = ps1, r2 = ps2, r3 = ps3;
    scan64_x4(r0, r1, r2, r3);

#define CHAIN(J, wvJ, rJ, psJ, mJ0, mJ1, mJ2, smJ)                                          \
    {                                                                                        \
      const float e0 = rJ - psJ;                                                             \
      const float e1 = e0 + mJ0;                                                             \
      const float e2 = e1 + mJ1;                                                             \
      const float e3 = e2 + mJ2;                                                             \
      float g0 = __builtin_amdgcn_rcpf(1.f + __builtin_amdgcn_exp2f(__builtin_fmaf(e0, -L2E, smJ))); \
      const float g1 = __builtin_amdgcn_rcpf(1.f + __builtin_amdgcn_exp2f(__builtin_fmaf(e1, -L2E, smJ))); \
      const float g2 = __builtin_amdgcn_rcpf(1.f + __builtin_amdgcn_exp2f(__builtin_fmaf(e2, -L2E, smJ))); \
      const float g3 = __builtin_amdgcn_rcpf(1.f + __builtin_amdgcn_exp2f(__builtin_fmaf(e3, -L2E, smJ))); \
      if (quirk && lane == 0) g0 = s2r[(hq << 5) + hl0 + J];                                 \
      z0 = __builtin_fmaf(g0, wvJ.x, z0);                                                    \
      z1 = __builtin_fmaf(g1, wvJ.y, z1);                                                    \
      z2 = __builtin_fmaf(g2, wvJ.z, z2);                                                    \
      z3 = __builtin_fmaf(g3, wvJ.w, z3);                                                    \
    }
    CHAIN(0, wv0, r0, ps0, m00, m01, m02, sm4.x)
    CHAIN(1, wv1, r1, ps1, m10, m11, m12, sm4.y)
    CHAIN(2, wv2, r2, ps2, m20, m21, m22, sm4.z)
    CHAIN(3, wv3, r3, ps3, m30, m31, m32, sm4.w)
#undef CHAIN
  }

  // cross-wave z reduction (reuse wt as zbuf[8][256])
  __syncthreads();
  {
    float4 zv; zv.x = z0; zv.y = z1; zv.z = z2; zv.w = z3;
    *reinterpret_cast<float4*>(&wt[w * 256 + 4 * lane]) = zv;
  }
  __syncthreads();

  if (tid < 256) {
    float zt = 0.f;
    #pragma unroll
    for (int ww = 0; ww < 8; ++ww) zt += wt[ww * 256 + tid];
    zt += Bv[base + tid];
    const float xf = x[(size_t)b * NFEAS + base + tid] > 0.f ? 1.f : 0.f;
    const float az = __builtin_fabsf(zt);
    const float ee = __builtin_amdgcn_exp2f(-L2E * az);
    const float li = fmaxf(zt, 0.f) - xf * zt +
                     LN2 * __builtin_amdgcn_logf(1.f + ee);
    const float tot = scan64(li);
    if ((tid & 63) == 63) lred[tid >> 6] = tot;
  }
  __syncthreads();
  if (tid == 0)
    losses[b * NC + c] = (lred[0] + lred[1]) + (lred[2] + lred[3]);
}

// ---------------------------------------------------------------------------
// Finalize: deterministic reduction of BATCH*NC chunk losses -> mean.
// ---------------------------------------------------------------------------
__global__ __launch_bounds__(256) void finalize_kernel(
    const float* __restrict__ losses, float* __restrict__ out)
{
  __shared__ float sm[256];
  const int t = threadIdx.x;
  float s = 0.f;
  for (int i = t; i < BATCH * NC; i += 256) s += losses[i];
  sm[t] = s;
  __syncthreads();
  for (int w = 128; w > 0; w >>= 1) {
    if (t < w) sm[t] += sm[t + w];
    __syncthreads();
  }
  if (t == 0) out[0] = sm[0] * (1.f / BATCH);
}

// ---------------------------------------------------------------------------
extern "C" void kernel_launch(void* const* d_in, const int* in_sizes, int n_in,
                              void* d_out, int out_size, void* d_ws, size_t ws_size,
                              hipStream_t stream)
{
  const float* x  = (const float*)d_in[0];  // [BATCH, NFEAS]
  const float* Cv = (const float*)d_in[1];  // [1, HID]
  const float* W  = (const float*)d_in[2];  // [NFEAS, HID]
  const float* Bv = (const float*)d_in[3];  // [NFEAS]
  float* out = (float*)d_out;

  float* T      = (float*)d_ws;                        // [B][HID][NSUB] 4 MB
  float* losses = T + (size_t)BATCH * HID * NSUB;      // [BATCH * NC]

  chunk_sums_kernel<<<dim3(NSUB, BATCH / 8), 128, 0, stream>>>(x, W, T);
  prefix_kernel<<<dim3(BATCH * HID / 4), 256, 0, stream>>>(T);
  scan_loss_kernel<<<dim3(BATCH, NC), 512, 0, stream>>>(x, Cv, W, Bv, T, losses);
  finalize_kernel<<<1, 256, 0, stream>>>(losses, out);
}